// Round 8
// baseline (313.903 us; speedup 1.0000x reference)
//
#include <hip/hip_runtime.h>

// Problem constants
#define T_ 64
#define P_ 144          // 12*12 windows per frame
#define NPAIR 9216      // T_*P_
#define C_ 1024
#define MID_ 256

typedef __attribute__((ext_vector_type(4))) float f32x4;
typedef __attribute__((ext_vector_type(8))) __bf16 bf16x8;
typedef __attribute__((ext_vector_type(4))) __bf16 bf16x4;

__device__ __forceinline__ void async_copy16(const void* g, void* l) {
  __builtin_amdgcn_global_load_lds(
      (const __attribute__((address_space(1))) unsigned int*)g,
      (__attribute__((address_space(3))) unsigned int*)l, 16, 0, 0);
}

// ---------------------------------------------------------------------------
// prep: blocks [0,64): Wq [1024][256] -> Wqt bf16 [256][1024] (transpose+cast)
//       blocks [64,96): Wk [1024][256] -> Wkb bf16 (cast only, layout kept)
__global__ __launch_bounds__(256) void prep_kernel(
    const float* __restrict__ Wq, const float* __restrict__ Wk,
    __bf16* __restrict__ Wqt, __bf16* __restrict__ Wkb) {
  const int bid = blockIdx.x;
  const int tid = threadIdx.x;
  if (bid < 64) {
    // transpose one 128c x 32d tile of Wq into Wqt
    const int ct = bid >> 3, dt = bid & 7;
    __shared__ float tile[128][33];
    const int r = tid >> 3;             // 0..31
    const int c4 = (tid & 7) * 4;       // 0..28
#pragma unroll
    for (int s = 0; s < 4; ++s) {
      const int row = r + s * 32;       // c within tile
      const f32x4 v =
          *(const f32x4*)(Wq + (size_t)(ct * 128 + row) * MID_ + dt * 32 + c4);
      tile[row][c4 + 0] = v[0]; tile[row][c4 + 1] = v[1];
      tile[row][c4 + 2] = v[2]; tile[row][c4 + 3] = v[3];
    }
    __syncthreads();
    const int dd = tid >> 5;            // 0..7
    const int cc4 = (tid & 31) * 4;     // 0..124
#pragma unroll
    for (int s = 0; s < 4; ++s) {
      const int d = dd + s * 8;
      bf16x4 o;
#pragma unroll
      for (int j = 0; j < 4; ++j) o[j] = (__bf16)tile[cc4 + j][d];
      *(bf16x4*)(Wqt + (size_t)(dt * 32 + d) * C_ + ct * 128 + cc4) = o;
    }
  } else {
    const int b = bid - 64;
    const float* src = Wk + (size_t)b * 8192;
    __bf16* dst = Wkb + (size_t)b * 8192;
#pragma unroll
    for (int s = 0; s < 8; ++s) {
      const f32x4 v = *(const f32x4*)(src + tid * 4 + s * 1024);
      bf16x4 o;
#pragma unroll
      for (int j = 0; j < 4; ++j) o[j] = (__bf16)v[j];
      *(bf16x4*)(dst + tid * 4 + s * 1024) = o;
    }
  }
}

// ---------------------------------------------------------------------------
// gemm_qp: q = mean-pool(img windows) @ Wqt^T + bq  (9216x256, K=1024) -> bf16
// Tile M=16 pairs x N=256 (full MID: img read exactly once). 576 blocks
// (2.25/CU), 256 threads / 4 waves, BK=32, 2-barrier K-steps.
// Staging wave-split: waves 0-1 pool A (img fp32 -> mean -> bf16 LDS),
// waves 2-3 stage the 16 KB Wqt slab via global_load_lds w16.
__global__ __launch_bounds__(256) void gemm_qp_kernel(
    const float* __restrict__ img, const __bf16* __restrict__ Wqt,
    const float* __restrict__ bq, __bf16* __restrict__ Q) {
  __shared__ __align__(16) __bf16 As[16 * 32];    //  1 KB A tile
  __shared__ __align__(16) __bf16 hs[256 * 32];   // 16 KB Wqt slab
  __shared__ float bqs[MID_];
  const int tid = threadIdx.x;
  const int bid = blockIdx.x;
  const int lane = tid & 63;
  const int wv = tid >> 6;              // 0..3
  const int quad = lane >> 4, lr = lane & 15;

  if (tid < MID_) bqs[tid] = bq[tid];

  // A-stager setup (tids 0..127): one (pair, ch-group) each
  const int pair = tid >> 3;            // 0..15
  const int chg = (tid & 7) * 4;        // 0,4,..28
  const int gp = bid * 16 + pair;
  const int t = gp / P_;
  const int pp = gp - t * P_;
  const int wy = pp / 12, wx = pp - wy * 12;
  const float* abase = img + ((size_t)t * 576 + 48 * wy + 2 * wx) * C_ + chg;
  __bf16* adst = As + pair * 32 + chg;

  // B-stager setup (tids 128..255): 8 copies of 16B each
  const int tb = tid - 128;             // 0..127
  const __bf16* gb = Wqt + (size_t)((tb * 2) >> 1) * 0;  // (placeholder opt-out)
  // unit u_i = tb + i*128: row = u_i>>2 (0..255), kq = u_i&3
  char* hdst = (char*)hs + tb * 16;

  f32x4 acc[4] = {};

  for (int it = 0; it < 32; ++it) {
    if (tid < 128) {
      const float* src = abase + it * 32;
      f32x4 sm = *(const f32x4*)(src);
      sm += *(const f32x4*)(src + C_);
      sm += *(const f32x4*)(src + 24 * C_);
      sm += *(const f32x4*)(src + 25 * C_);
      sm *= 0.25f;
      bf16x4 pv;
#pragma unroll
      for (int q = 0; q < 4; ++q) pv[q] = (__bf16)sm[q];
      *(bf16x4*)(adst) = pv;
    } else {
#pragma unroll
      for (int i = 0; i < 8; ++i) {
        const int u = tb + i * 128;
        const __bf16* src = Wqt + (size_t)(u >> 2) * C_ + (u & 3) * 8 + it * 32;
        async_copy16(src, hdst + i * 2048);
      }
    }
    __syncthreads();    // A written, slab landed (+ bqs on it=0)
    const bf16x8 a = *(const bf16x8*)(As + lr * 32 + quad * 8);
#pragma unroll
    for (int j = 0; j < 4; ++j) {
      const bf16x8 b = *(const bf16x8*)(hs + (wv * 64 + j * 16 + lr) * 32 + quad * 8);
      acc[j] = __builtin_amdgcn_mfma_f32_16x16x32_bf16(a, b, acc[j], 0, 0, 0);
    }
    __syncthreads();    // reads done before next overwrite
  }
  (void)gb;

  // epilogue: C/D map col=lr(+j*16+wv*64), row(pair)=quad*4+r
#pragma unroll
  for (int j = 0; j < 4; ++j) {
    const int col = wv * 64 + j * 16 + lr;
    const float bv = bqs[col];
#pragma unroll
    for (int r = 0; r < 4; ++r) {
      const int row = quad * 4 + r;     // pair index within block
      Q[((size_t)bid * 16 + row) * MID_ + col] = (__bf16)(acc[j][r] + bv);
    }
  }
}

// ---------------------------------------------------------------------------
// gemm_u: u = q @ Wkb^T   (9216x1024, K=256) -> bf16. grid 72x8 = 576 blocks.
__global__ __launch_bounds__(256) void gemm_u_kernel(
    const __bf16* __restrict__ A, const __bf16* __restrict__ Bt,
    __bf16* __restrict__ U) {
  __shared__ __align__(16) __bf16 As[128 * 32];
  __shared__ __align__(16) __bf16 Bs[128 * 32];
  const int bid = blockIdx.x;
  const int mt = bid >> 3, nt = bid & 7;
  const int tid = threadIdx.x;
  const int lane = tid & 63;
  const int wv = tid >> 6;
  const int quad = lane >> 4, lr = lane & 15;
  const int wm = wv >> 1, wn = wv & 1;

  const int r0 = tid >> 2, p0 = tid & 3;
  const int wvb = (tid & ~63) * 16;
  const __bf16* ga0 = A + ((size_t)mt * 128 + r0) * (size_t)MID_ + p0 * 8;
  const __bf16* ga1 = ga0 + (size_t)64 * MID_;
  const __bf16* gb0 = Bt + ((size_t)nt * 128 + r0) * (size_t)MID_ + p0 * 8;
  const __bf16* gb1 = gb0 + (size_t)64 * MID_;
  char* AsB0 = (char*)As + wvb;
  char* AsB1 = (char*)As + 4096 + wvb;
  char* BsB0 = (char*)Bs + wvb;
  char* BsB1 = (char*)Bs + 4096 + wvb;

  f32x4 acc[4][4] = {};

  for (int it = 0; it < 8; ++it) {
    async_copy16(ga0, AsB0);
    async_copy16(ga1, AsB1);
    async_copy16(gb0, BsB0);
    async_copy16(gb1, BsB1);
    ga0 += 32; ga1 += 32; gb0 += 32; gb1 += 32;
    __syncthreads();
    bf16x8 a[4], b[4];
    const bf16x8* Ap = (const bf16x8*)As;
    const bf16x8* Bp = (const bf16x8*)Bs;
#pragma unroll
    for (int i = 0; i < 4; ++i) {
      a[i] = Ap[(wm * 64 + i * 16 + lr) * 4 + quad];
      b[i] = Bp[(wn * 64 + i * 16 + lr) * 4 + quad];
    }
#pragma unroll
    for (int mi = 0; mi < 4; ++mi)
#pragma unroll
      for (int ni = 0; ni < 4; ++ni)
        acc[mi][ni] = __builtin_amdgcn_mfma_f32_16x16x32_bf16(
            a[mi], b[ni], acc[mi][ni], 0, 0, 0);
    __syncthreads();
  }

  const int colb = nt * 128 + wn * 64;
  const int rowb = mt * 128 + wm * 64 + quad * 4;
#pragma unroll
  for (int ni = 0; ni < 4; ++ni) {
    const int col = colb + ni * 16 + lr;
#pragma unroll
    for (int mi = 0; mi < 4; ++mi) {
      const int row = rowb + mi * 16;
#pragma unroll
      for (int r = 0; r < 4; ++r)
        U[(size_t)(row + r) * C_ + col] = (__bf16)acc[mi][ni][r];
    }
  }
}

// ---------------------------------------------------------------------------
// attn: one PAIR per WAVE (4 pairs/block, 2304 blocks): no barriers, no LDS.
__global__ __launch_bounds__(256) void attn_out_kernel(
    const __bf16* __restrict__ U, const float* __restrict__ img,
    float* __restrict__ out) {
  const int tid = threadIdx.x;
  const int wv = tid >> 6, lane = tid & 63;
  const int pair = blockIdx.x * 4 + wv;
  const int t = pair / P_;
  const int pp = pair - t * P_;
  const int wy = pp / 12, wx = pp - wy * 12;
  const float* base = img + ((size_t)t * 576 + 48 * wy + 2 * wx) * C_;

  f32x4 v0[4], v1[4], v2[4], v3[4], u4[4];
  float pd0 = 0.f, pd1 = 0.f, pd2 = 0.f, pd3 = 0.f;
#pragma unroll
  for (int ch = 0; ch < 4; ++ch) {
    const int c = lane * 4 + ch * 256;
    v0[ch] = *(const f32x4*)(base + c);
    v1[ch] = *(const f32x4*)(base + (size_t)1 * C_ + c);
    v2[ch] = *(const f32x4*)(base + (size_t)24 * C_ + c);
    v3[ch] = *(const f32x4*)(base + (size_t)25 * C_ + c);
    const bf16x4 ub = *(const bf16x4*)(U + (size_t)pair * C_ + c);
#pragma unroll
    for (int j = 0; j < 4; ++j) u4[ch][j] = (float)ub[j];
#pragma unroll
    for (int j = 0; j < 4; ++j) {
      pd0 += u4[ch][j] * v0[ch][j];
      pd1 += u4[ch][j] * v1[ch][j];
      pd2 += u4[ch][j] * v2[ch][j];
      pd3 += u4[ch][j] * v3[ch][j];
    }
  }
#pragma unroll
  for (int m = 32; m >= 1; m >>= 1) {
    pd0 += __shfl_xor(pd0, m);
    pd1 += __shfl_xor(pd1, m);
    pd2 += __shfl_xor(pd2, m);
    pd3 += __shfl_xor(pd3, m);
  }
  const float l0 = pd0 * 0.0625f, l1 = pd1 * 0.0625f;
  const float l2 = pd2 * 0.0625f, l3 = pd3 * 0.0625f;
  const float mx = fmaxf(fmaxf(l0, l1), fmaxf(l2, l3));
  const float e0 = __expf(l0 - mx), e1 = __expf(l1 - mx);
  const float e2 = __expf(l2 - mx), e3 = __expf(l3 - mx);
  const float inv = 1.f / (e0 + e1 + e2 + e3);
  const float a0 = e0 * inv + 0.25f, a1 = e1 * inv + 0.25f;
  const float a2 = e2 * inv + 0.25f, a3 = e3 * inv + 0.25f;
  float* op = out + (size_t)pair * C_;
#pragma unroll
  for (int ch = 0; ch < 4; ++ch) {
    const int c = lane * 4 + ch * 256;
    f32x4 o = a0 * v0[ch] + a1 * v1[ch] + a2 * v2[ch] + a3 * v3[ch];
    *(f32x4*)(op + c) = o;
  }
}

// ---------------------------------------------------------------------------
extern "C" void kernel_launch(void* const* d_in, const int* in_sizes, int n_in,
                              void* d_out, int out_size, void* d_ws,
                              size_t ws_size, hipStream_t stream) {
  const float* img = (const float*)d_in[0];
  const float* Wq = (const float*)d_in[1];
  const float* bq = (const float*)d_in[2];
  const float* Wk = (const float*)d_in[3];
  const float* bk = (const float*)d_in[4];  // constant under softmax -> unused
  (void)bk;
  float* out = (float*)d_out;

  // workspace layout (~24.7 MB)
  char* ws = (char*)d_ws;
  __bf16* Wqt = (__bf16*)ws;                 //  256*1024*2 =    524,288
  __bf16* Wkb = (__bf16*)(ws + 524288);      //  1024*256*2 =    524,288
  __bf16* Qb  = (__bf16*)(ws + 1048576);     //  9216*256*2 =  4,718,592
  __bf16* U   = (__bf16*)(ws + 5767168);     //  9216*1024*2= 18,874,368

  // 1) weights: Wq -> Wqt (bf16 transpose), Wk -> Wkb (bf16 cast)
  prep_kernel<<<96, 256, 0, stream>>>(Wq, Wk, Wqt, Wkb);
  // 2) q = pool(img) @ Wq + bq  (pooling fused into A-staging; img read once)
  gemm_qp_kernel<<<576, 256, 0, stream>>>(img, Wqt, bq, Qb);
  // 3) u = q @ Wk^T
  gemm_u_kernel<<<576, 256, 0, stream>>>(Qb, Wkb, U);
  // 4) logits, softmax, weighted output (1 pair/wave, no barriers)
  attn_out_kernel<<<NPAIR / 4, 256, 0, stream>>>(U, img, out);
}